// Round 6
// baseline (330.129 us; speedup 1.0000x reference)
//
#include <hip/hip_runtime.h>
#include <hip/hip_bf16.h>
#include <stdint.h>

// Problem constants
#define BT    (256*2048)      // 524288 tokens
#define DIN   25
#define DP    128
#define MTILE 128             // tokens per tile (4 waves x 32 tokens)
#define NTILE (BT/MTILE)      // 4096 tiles
#define NBLK  1024            // persistent blocks; 4 tiles each
#define TPB   (NTILE/NBLK)    // 4 tiles per block
#define HBYTES 32768          // h: 128 rows x 256 B (XOR-swizzled bf16[128])
#define XSTG   12800          // one x stage buffer: 128 rows x 100 B
#define SM_BYTES (HBYTES + 2*XSTG)   // 58368 B -> 2 blocks/CU (LDS-capped)

typedef __attribute__((ext_vector_type(8))) __bf16 bf16x8;
typedef __attribute__((ext_vector_type(4))) __bf16 bf16x4;
typedef __attribute__((ext_vector_type(4))) float  f32x4;
typedef __attribute__((ext_vector_type(2))) float  f32x2;

__device__ __forceinline__ unsigned short f2bf(float f) {
  unsigned int u = __float_as_uint(f);
  u += 0x7fffu + ((u >> 16) & 1u);          // round-to-nearest-even
  return (unsigned short)(u >> 16);
}

// exact-erf GELU via Abramowitz&Stegun 7.1.26 (|eps|<=1.5e-7), ~15 VALU ops
__device__ __forceinline__ float gelu_exact(float x) {
  float z  = 0.70710678118654752f * x;
  float az = __builtin_fabsf(z);
  float t  = __builtin_amdgcn_rcpf(1.0f + 0.3275911f * az);
  float p  = t*(0.254829592f + t*(-0.284496736f + t*(1.421413741f +
             t*(-1.453152027f + t*1.061405429f))));
  float e  = __expf(-z*z);                  // v_exp_f32 path
  float erf_az = 1.0f - p*e;
  float erf_z  = (x < 0.f) ? -erf_az : erf_az;
  return 0.5f * x * (1.0f + erf_z);
}

__device__ __forceinline__ void async16(void* lds, const void* g) {
  __builtin_amdgcn_global_load_lds(
      (const __attribute__((address_space(1))) unsigned int*)g,
      (__attribute__((address_space(3)))       unsigned int*)lds, 16, 0, 0);
}

// ---------------------------------------------------------------------------
// Prep: pack w1/w2 into bf16 MFMA B-frags with COLUMN-PERMUTED lane ownership.
// B-frag (16x16x32): elem(lane,j) sits at (k=(lane>>4)*8+j, frag-n=lane&15).
//  w1 frag f (0..7):  frag-n l -> true col n1 = (f>>2)*64 + l*4 + (f&3)
//     => lane l15 owns 4 ADJACENT h cols -> b64 h writes
//  w2 frag F (0..7):  frag-n l -> true col n2 = (F>>1)*32 + l*2 + (F&1)
//     => lane l15 owns 2 ADJACENT out cols -> dwordx2 out stores
// Layout: wf[0..8KB) = w1 frags f*1KB ; wf[8KB + (F*4+ks)*1KB) = w2 (ks = K/32)
// ---------------------------------------------------------------------------
__global__ void prep_kernel(const float* __restrict__ w1, const float* __restrict__ w2,
                            unsigned short* __restrict__ wf) {
  int idx = blockIdx.x * 256 + threadIdx.x;
  if (idx >= 40 * 512) return;
  int f = idx >> 9, r = idx & 511, l = r >> 3, j = r & 7;
  int l15 = l & 15, kq = (l >> 4) * 8 + j;
  float val;
  if (f < 8) {                       // w1 frag f
    int n = (f >> 2) * 64 + l15 * 4 + (f & 3);
    val = (kq < DIN) ? w1[kq * DP + n] : 0.f;
  } else {                           // w2 frag: q = F*4 + ks
    int q = f - 8, F = q >> 2, ks = q & 3;
    int k = ks * 32 + kq;
    int n = (F >> 1) * 32 + l15 * 2 + (F & 1);
    val = w2[k * DP + n];
  }
  wf[idx] = f2bf(val);
}

// ---------------------------------------------------------------------------
// Persistent-block fused LN -> mm1(+b1,GELU) -> mm2(+b2).
// Each block loops TPB tiles; next tile's x is prefetched (async16 into a
// dedicated double-buffer, per-wave slices) while the current tile computes.
// Weights/biases loaded once per block. Two __syncthreads per tile protect
// the shared h tile (full fences; x region is wave-private).
// ---------------------------------------------------------------------------
__global__ __launch_bounds__(256, 2) void fused_kernel(
    const float* __restrict__ x,   const float* __restrict__ gam,
    const float* __restrict__ bet, const float* __restrict__ b1,
    const float* __restrict__ b2,  const unsigned short* __restrict__ wfr,
    float* __restrict__ out) {
  __shared__ __align__(16) unsigned char smem[SM_BYTES];
  const int tid  = threadIdx.x;
  const int lane = tid & 63, w = tid >> 6;
  const int quad = lane >> 4, l15 = lane & 15;
  const int kbase = quad * 8;
  const long long tile0 = (long long)blockIdx.x * TPB;
  unsigned char* band = smem + w * 8192;                 // wave's h rows (32x256B)
  const unsigned char* wfb = (const unsigned char*)wfr;
  const unsigned char* xb  = (const unsigned char*)x;

  // ---- per-wave x stage: 32 rows = 3200 B = 200 x 16B chunks ----
  auto STAGE = [&](int ti, int sbuf) {
    const unsigned char* src = xb + ((tile0 + ti) * 128LL + w * 32) * 100;
    unsigned char* dst = smem + HBYTES + sbuf * XSTG + w * 3200;
#pragma unroll
    for (int i2 = 0; i2 < 4; i2++) {
      int c = lane + i2 * 64;
      if (c < 200) async16(dst + c * 16, src + c * 16);
    }
  };

  STAGE(0, 0);                                   // prologue prefetch

  // ---- loop-invariant preloads (once per block, overlap the prologue) ----
  float gk[8], bk[8];
#pragma unroll
  for (int j = 0; j < 8; j++) {
    int k = kbase + j;
    bool v = (k < DIN);
    gk[j] = v ? gam[k] : 0.f;
    bk[j] = v ? bet[k] : 0.f;
  }
  bf16x8 wb1[8];
#pragma unroll
  for (int f = 0; f < 8; f++)
    wb1[f] = *(const bf16x8*)(wfb + f * 1024 + lane * 16);
  float b1v[8];                                  // bias at true col n1(f,l15)
#pragma unroll
  for (int f = 0; f < 8; f++)
    b1v[f] = b1[(f >> 2) * 64 + l15 * 4 + (f & 3)];
  bf16x8 wb2[2][4];
#pragma unroll
  for (int ni = 0; ni < 2; ni++)
#pragma unroll
    for (int ks = 0; ks < 4; ks++)
      wb2[ni][ks] = *(const bf16x8*)(wfb + 8192 + (((w * 2 + ni) * 4) + ks) * 1024 + lane * 16);
  f32x2 bias2 = *(const f32x2*)(b2 + w * 32 + 2 * l15);

  const f32x4 zf = {0.f, 0.f, 0.f, 0.f};

  for (int it = 0; it < TPB; it++) {
    const int s = it & 1;
    // prefetch next tile (dummy = tile 0 of this block on last iter: harmless)
    STAGE((it + 1 < TPB) ? it + 1 : 0, s ^ 1);
    // wait current tile's stage (the 4 newest loads are next-tile's)
    asm volatile("s_waitcnt vmcnt(4)" ::: "memory");
    __builtin_amdgcn_sched_barrier(0);

    // ---- LN fused into A-frag build (two-pass variance, regs + shfl) ----
    const float* xs = (const float*)(smem + HBYTES + s * XSTG + w * 3200);
    bf16x8 afrag[2];
#pragma unroll
    for (int t = 0; t < 2; t++) {
      float xv[8];
      float sum = 0.f;
#pragma unroll
      for (int j = 0; j < 8; j++) {
        int k = kbase + j;
        float v = 0.f;
        if (k < DIN) v = xs[(t * 16 + l15) * DIN + k];
        xv[j] = v;
        sum += v;
      }
      sum += __shfl_xor(sum, 16);  sum += __shfl_xor(sum, 32);
      float mu = sum * (1.f / DIN);
      float vv = 0.f;
#pragma unroll
      for (int j = 0; j < 8; j++) {
        int k = kbase + j;
        float d = (k < DIN) ? (xv[j] - mu) : 0.f;
        vv += d * d;
      }
      vv += __shfl_xor(vv, 16); vv += __shfl_xor(vv, 32);
      float inv = rsqrtf(vv * (1.f / DIN) + 1e-5f);
      bf16x8 av;
#pragma unroll
      for (int j = 0; j < 8; j++)
        av[j] = (__bf16)((xv[j] - mu) * inv * gk[j] + bk[j]);   // gk=bk=0 on pad
      afrag[t] = av;
    }

    // ---- mm1: 2 tiles x 2 col-groups of 4 frags; b64 swizzled h writes ----
#pragma unroll
    for (int t = 0; t < 2; t++) {
#pragma unroll
      for (int cg = 0; cg < 2; cg++) {
        f32x4 acc[4];
#pragma unroll
        for (int c = 0; c < 4; c++)
          acc[c] = __builtin_amdgcn_mfma_f32_16x16x32_bf16(afrag[t], wb1[cg * 4 + c], zf, 0, 0, 0);
#pragma unroll
        for (int r = 0; r < 4; r++) {
          int rl  = t * 16 + quad * 4 + r;           // row within band (0..31)
          int swz = ((quad * 4 + r) & 7) << 4;       // rl&7 == (quad*4+r)&7
          bf16x4 hv;
#pragma unroll
          for (int c = 0; c < 4; c++)
            hv[c] = (__bf16)gelu_exact(acc[c][r] + b1v[cg * 4 + c]);
          *(bf16x4*)(band + rl * 256 + ((cg * 128 + l15 * 8) ^ swz)) = hv;
        }
      }
    }

    __syncthreads();   // h ready block-wide (full fence; also drains prefetch)

    // ---- mm2: out = h @ w2 + b2. Wave w owns out cols [w*32, w*32+32) ----
    const long long orow0 = (tile0 + it) * MTILE;
    const int rswz = (l15 & 7) << 4;               // row = mt*16+l15 -> row&7 = l15&7
#pragma unroll
    for (int mt = 0; mt < 8; mt++) {
      bf16x8 af[4];
#pragma unroll
      for (int ks = 0; ks < 4; ks++)
        af[ks] = *(const bf16x8*)(smem + (mt * 16 + l15) * 256 + ((ks * 64 + quad * 16) ^ rswz));
      f32x4 a0 = zf, a1 = zf;
#pragma unroll
      for (int ks = 0; ks < 4; ks++) {
        a0 = __builtin_amdgcn_mfma_f32_16x16x32_bf16(af[ks], wb2[0][ks], a0, 0, 0, 0);
        a1 = __builtin_amdgcn_mfma_f32_16x16x32_bf16(af[ks], wb2[1][ks], a1, 0, 0, 0);
      }
      float* orow = out + (orow0 + mt * 16) * DP + w * 32 + 2 * l15;
#pragma unroll
      for (int r = 0; r < 4; r++) {
        int row = quad * 4 + r;
        f32x2 o; o[0] = a0[r] + bias2[0]; o[1] = a1[r] + bias2[1];
        *(f32x2*)(orow + row * DP) = o;            // adjacent cols: dwordx2
      }
    }

    __syncthreads();   // all reads of h done before next iter overwrites it
  }
}

extern "C" void kernel_launch(void* const* d_in, const int* in_sizes, int n_in,
                              void* d_out, int out_size, void* d_ws, size_t ws_size,
                              hipStream_t stream) {
  const float* x   = (const float*)d_in[0];
  const float* gam = (const float*)d_in[1];
  const float* bet = (const float*)d_in[2];
  const float* w1  = (const float*)d_in[3];
  const float* b1  = (const float*)d_in[4];
  const float* w2  = (const float*)d_in[5];
  const float* b2  = (const float*)d_in[6];
  float* out = (float*)d_out;
  unsigned short* wf = (unsigned short*)d_ws;   // 40KB of packed bf16 weight frags

  prep_kernel<<<80, 256, 0, stream>>>(w1, w2, wf);
  fused_kernel<<<NBLK, 256, 0, stream>>>(x, gam, bet, b1, b2, wf, out);
}